// Round 10
// baseline (353.146 us; speedup 1.0000x reference)
//
#include <hip/hip_runtime.h>
#include <math.h>

#define BATCH 16
#define SEQ   1024
#define HID   441
#define NH    9
#define KP    448                 // padded hidden (K and N dim of GEMMs)
#define PB    544                 // sum of padded head dims
#define PBE   (SEQ * PB)          // padded elems per batch
#define WTS   (KP * KP)           // one transposed weight matrix

typedef __attribute__((ext_vector_type(8))) short bf16x8;
typedef __attribute__((ext_vector_type(4))) float f32x4;

__constant__ int c_bounds[NH + 1] = {0, 7, 21, 49, 105, 161, 217, 273, 357, 441};
__constant__ int c_dpad[NH] = {32, 32, 32, 64, 64, 64, 64, 96, 96};
__constant__ int c_cum[NH]  = {0, 32, 64, 96, 160, 224, 288, 352, 448};

__device__ __forceinline__ ushort f2bf(float x) {
    union { float f; unsigned u; } v; v.f = x;
    unsigned r = v.u + 0x7FFF + ((v.u >> 16) & 1);   // RNE
    return (ushort)(r >> 16);
}

__device__ __forceinline__ void gld_lds16(const ushort* g, ushort* l) {
    __builtin_amdgcn_global_load_lds(
        (const __attribute__((address_space(1))) unsigned int*)g,
        (__attribute__((address_space(3))) unsigned int*)l, 16, 0, 0);
}

// ---------------------------------------------------------------------------
// hs fp32 [16384][441] -> bf16 [16384][448] (pad cols zeroed)
// ---------------------------------------------------------------------------
__global__ __launch_bounds__(256)
void convert_hs(const float* __restrict__ hs, ushort* __restrict__ out)
{
    int t = blockIdx.x * 256 + threadIdx.x;   // 16384*56 threads
    int r = t / 56, cc = t % 56;
    const float* src = hs + (size_t)r * HID + cc * 8;
    union { ushort u[8]; bf16x8 v; } pk;
#pragma unroll
    for (int j = 0; j < 8; ++j) {
        int c = cc * 8 + j;
        pk.u[j] = (c < HID) ? f2bf(src[j]) : (ushort)0;
    }
    *(bf16x8*)(out + (size_t)r * KP + cc * 8) = pk.v;
}

// ---------------------------------------------------------------------------
// W fp32 [441][441] -> W^T bf16 [448][448] (pads zero). blockIdx.y = matrix.
// ---------------------------------------------------------------------------
__global__ __launch_bounds__(256)
void convert_w(const float* __restrict__ W0, const float* __restrict__ W1,
               const float* __restrict__ W2, const float* __restrict__ W3,
               ushort* __restrict__ wt)
{
    const float* W = (blockIdx.y == 0) ? W0 : (blockIdx.y == 1) ? W1
                   : (blockIdx.y == 2) ? W2 : W3;
    ushort* out = wt + (size_t)blockIdx.y * WTS;
    int t = blockIdx.x * 256 + threadIdx.x;   // 448*56 threads
    int n = t / 56, kc = t % 56;
    union { ushort u[8]; bf16x8 v; } pk;
#pragma unroll
    for (int j = 0; j < 8; ++j) {
        int k = kc * 8 + j;
        pk.u[j] = (k < HID && n < HID) ? f2bf(W[(size_t)k * HID + n]) : (ushort)0;
    }
    *(bf16x8*)(out + (size_t)n * KP + kc * 8) = pk.v;
}

// ---------------------------------------------------------------------------
// bf16 MFMA GEMM: C[16384, 448] = A[16384, 448] @ Bt[448, 448]^T + bias
// Tile 128x64, BK=32, 4 waves (2x2), global_load_lds staging, 1 barrier/step.
// MODE 0: Q — bf16 scatter -> padded [b][h][s][dp], PRE-SCALED by log2e/sqrt(d)
// MODE 3: K — bf16 scatter -> padded [b][h][s][dp], unscaled
// MODE 1: V — bf16 scatter -> transposed [b][h][dv][s]
// MODE 2: O — fp32 row-major [16384][441] + bias
// ---------------------------------------------------------------------------
template<int MODE>
__global__ __launch_bounds__(256)
void gemm_mfma(const ushort* __restrict__ A, const ushort* __restrict__ Bt,
               const float* __restrict__ bias, void* __restrict__ Cout)
{
    __shared__ ushort As[2][128 * 32];   // per buffer: 128 rows x 32 K = 4096 ushorts
    __shared__ ushort Bs[2][64 * 32];

    int tid = threadIdx.x;
    int wid = tid >> 6, lane = tid & 63;
    int wm = wid >> 1, wn = wid & 1;
    int lr = lane & 15, lg = lane >> 4;
    int m0 = blockIdx.x * 128, n0 = blockIdx.y * 64;

    const ushort* a_src = A + (size_t)(m0 + (tid >> 2)) * KP + (tid & 3) * 8;
    const ushort* b_src = Bt + (size_t)(n0 + (tid >> 2)) * KP + (tid & 3) * 8;

    f32x4 acc[4][2];
#pragma unroll
    for (int i = 0; i < 4; ++i)
#pragma unroll
        for (int j = 0; j < 2; ++j) acc[i][j] = (f32x4){0.f, 0.f, 0.f, 0.f};

    auto stage = [&](int buf, int k0) {
        gld_lds16(a_src + k0,            &As[buf][tid * 8]);
        gld_lds16(a_src + 64 * KP + k0,  &As[buf][2048 + tid * 8]);
        gld_lds16(b_src + k0,            &Bs[buf][tid * 8]);
    };

    stage(0, 0);
#pragma unroll 2
    for (int t = 0; t < 14; ++t) {
        int buf = t & 1;
        __syncthreads();                       // drains vmcnt+lgkm: buf staged, prev reads done
        if (t < 13) stage(buf ^ 1, (t + 1) * 32);

        bf16x8 af[4], bf[2];
#pragma unroll
        for (int mr = 0; mr < 4; ++mr)
            af[mr] = *(const bf16x8*)&As[buf][(wm * 64 + mr * 16 + lr) * 32 + lg * 8];
#pragma unroll
        for (int nt = 0; nt < 2; ++nt)
            bf[nt] = *(const bf16x8*)&Bs[buf][(wn * 32 + nt * 16 + lr) * 32 + lg * 8];
#pragma unroll
        for (int mr = 0; mr < 4; ++mr)
#pragma unroll
            for (int nt = 0; nt < 2; ++nt)
                acc[mr][nt] = __builtin_amdgcn_mfma_f32_16x16x32_bf16(af[mr], bf[nt], acc[mr][nt], 0, 0, 0);
    }

    // ---- epilogue ----
    int bb = m0 >> 10;
    int srow = (m0 & 1023) + wm * 64;

#pragma unroll
    for (int nt = 0; nt < 2; ++nt) {
        int gn = n0 + wn * 32 + nt * 16 + lr;
        bool ok = gn < HID;
        int gcl = ok ? gn : 0;
        float bval = ok ? bias[gcl] : 0.f;
        int hh = 0;
        while (gcl >= c_bounds[hh + 1]) ++hh;
        int off = gcl - c_bounds[hh];
        int dph = c_dpad[hh];
        size_t hbase = (size_t)bb * PBE + ((size_t)c_cum[hh] << 10);
        // Q pre-scale: fold log2e / sqrt(d) into Q so attention needs no score mul
        float cs = (MODE == 0)
                 ? rsqrtf((float)(c_bounds[hh + 1] - c_bounds[hh])) * 1.44269504f
                 : 1.0f;

#pragma unroll
        for (int mr = 0; mr < 4; ++mr)
#pragma unroll
            for (int r = 0; r < 4; ++r) {
                if (!ok) continue;
                int s = srow + mr * 16 + lg * 4 + r;
                float val = (acc[mr][nt][r] + bval) * cs;
                if (MODE == 0 || MODE == 3) {
                    ((ushort*)Cout)[hbase + (size_t)s * dph + off] = f2bf(val);
                } else if (MODE == 1) {
                    ((ushort*)Cout)[hbase + ((size_t)off << 10) + s] = f2bf(val);
                } else {
                    ((float*)Cout)[(size_t)(m0 + wm * 64 + mr * 16 + lg * 4 + r) * HID + gn] = val;
                }
            }
    }
}

// ---------------------------------------------------------------------------
// MFMA flash attention. 2-wave WGs, barrier-free, waves independent.
// SOFTWARE-PIPELINED register prefetch: key-tile loop unrolled x2 with named
// A/B register sets; prefetch of tile t+1 issued BEFORE compute of tile t and
// PINNED with sched_barrier(0) so the compiler cannot sink the loads (R8's
// attempt was defeated exactly this way — VGPR stayed 72).
// __launch_bounds__(128,2) -> 256-VGPR budget for the two fragment sets.
// Q pre-scaled (exp2 domain); K[s][DP] padded; V TRANSPOSED [dv][1024].
// ---------------------------------------------------------------------------
template<int DP, int KVB>
__device__ __forceinline__
void attn_body(const ushort* __restrict__ qp, const ushort* __restrict__ kp,
               const ushort* __restrict__ vp, ushort* __restrict__ ctx,
               ushort* __restrict__ Ps, int h, int b, int q0)
{
    constexpr int NDT = DP / 16;         // output col tiles (2/4/6)
    constexpr int NXC = DP / 32;         // K-dim chunks for QK (1/2/3)
    constexpr int NCT = KVB / 16;        // key sub-tiles per tile (4 or 2)
    constexpr int NKS = KVB / 32;        // PV K-chunks per tile (2 or 1)
    constexpr int M   = KVB / 8 - 1;     // Ps swizzle mask (7 or 3)

    int lane = threadIdx.x & 63;
    int lr = lane & 15, lg = lane >> 4;

    int s0 = c_bounds[h];
    int d  = c_bounds[h + 1] - s0;

    size_t base = (size_t)b * PBE + ((size_t)c_cum[h] << 10);
    const ushort* Q   = qp + base;
    const ushort* Kb  = kp + base;
    const ushort* Vtb = vp + base;

    int swz = (lr & M) << 3;

    bf16x8 aq[NXC];
    {
        int qrow = q0 + lr;
        const ushort* qr = Q + (size_t)qrow * DP + lg * 8;
#pragma unroll
        for (int xc = 0; xc < NXC; ++xc)
            aq[xc] = *(const bf16x8*)(qr + xc * 32);
    }

    f32x4 o[NDT];
#pragma unroll
    for (int i = 0; i < NDT; ++i) o[i] = (f32x4){0.f, 0.f, 0.f, 0.f};
    float mrow[4] = {-1e30f, -1e30f, -1e30f, -1e30f};
    float lrow[4] = {0.f, 0.f, 0.f, 0.f};

    // two named register sets (static indices only — rule #20)
    bf16x8 kfA[NCT][NXC], vfA[NDT][NKS];
    bf16x8 kfB[NCT][NXC], vfB[NDT][NKS];

    auto loadset = [&](bf16x8 (&kf)[NCT][NXC], bf16x8 (&vf)[NDT][NKS], int kt) {
#pragma unroll
        for (int ct = 0; ct < NCT; ++ct) {
            const ushort* kr = Kb + (size_t)(kt + ct * 16 + lr) * DP + lg * 8;
#pragma unroll
            for (int xc = 0; xc < NXC; ++xc)
                kf[ct][xc] = *(const bf16x8*)(kr + xc * 32);
        }
#pragma unroll
        for (int dt = 0; dt < NDT; ++dt) {
            const ushort* vr = Vtb + ((size_t)(dt * 16 + lr) << 10) + kt + lg * 8;
#pragma unroll
            for (int ks = 0; ks < NKS; ++ks)
                vf[dt][ks] = *(const bf16x8*)(vr + ks * 32);
        }
    };

    auto compute = [&](bf16x8 (&kf)[NCT][NXC], bf16x8 (&vf)[NDT][NKS]) {
        // ---- S = Q K^T (already exp2-scaled via Q) ----
        f32x4 sc[NCT];
        __builtin_amdgcn_s_setprio(1);
#pragma unroll
        for (int ct = 0; ct < NCT; ++ct) {
            f32x4 s = {0.f, 0.f, 0.f, 0.f};
#pragma unroll
            for (int xc = 0; xc < NXC; ++xc)
                s = __builtin_amdgcn_mfma_f32_16x16x32_bf16(aq[xc], kf[ct][xc], s, 0, 0, 0);
            sc[ct] = s;
        }
        __builtin_amdgcn_s_setprio(0);

        // ---- online softmax ----
        float mnew[4], fr[4];
#pragma unroll
        for (int r = 0; r < 4; ++r) {
            float mx = sc[0][r];
#pragma unroll
            for (int ct = 1; ct < NCT; ++ct) mx = fmaxf(mx, sc[ct][r]);
#pragma unroll
            for (int off = 1; off < 16; off <<= 1)
                mx = fmaxf(mx, __shfl_xor(mx, off));
            mnew[r] = fmaxf(mrow[r], mx);
            fr[r] = exp2f(mrow[r] - mnew[r]);
            mrow[r] = mnew[r];
        }
#pragma unroll
        for (int r = 0; r < 4; ++r) {
            int row = lg * 4 + r;
            int wsz = (row & M) << 3;
            float sum = 0.f;
#pragma unroll
            for (int ct = 0; ct < NCT; ++ct) {
                float p = exp2f(sc[ct][r] - mnew[r]);
                sum += p;
                // round-half-up bf16 (2 VALU ops; no systematic bias)
                Ps[row * KVB + ((lr + ct * 16) ^ wsz)] =
                    (ushort)((__builtin_bit_cast(unsigned, p) + 0x8000u) >> 16);
            }
#pragma unroll
            for (int off = 1; off < 16; off <<= 1)
                sum += __shfl_xor(sum, off);
            lrow[r] = lrow[r] * fr[r] + sum;
        }

        // ---- O = fr*O + P V ----
        bf16x8 ap[NKS];
#pragma unroll
        for (int ks = 0; ks < NKS; ++ks)
            ap[ks] = *(const bf16x8*)&Ps[lr * KVB + ((ks * 32 + lg * 8) ^ swz)];

        __builtin_amdgcn_s_setprio(1);
#pragma unroll
        for (int dt = 0; dt < NDT; ++dt) {
#pragma unroll
            for (int r = 0; r < 4; ++r) o[dt][r] *= fr[r];
#pragma unroll
            for (int ks = 0; ks < NKS; ++ks)
                o[dt] = __builtin_amdgcn_mfma_f32_16x16x32_bf16(ap[ks], vf[dt][ks], o[dt], 0, 0, 0);
        }
        __builtin_amdgcn_s_setprio(0);
    };

    loadset(kfA, vfA, 0);
    for (int kt = 0; kt < SEQ; kt += 2 * KVB) {
        // prefetch tile kt+KVB, pin issue point, compute tile kt
        loadset(kfB, vfB, (kt + KVB) & (SEQ - 1));
        __builtin_amdgcn_sched_barrier(0);
        compute(kfA, vfA);
        // prefetch tile kt+2*KVB (wraps harmlessly on last iter), compute kt+KVB
        loadset(kfA, vfA, (kt + 2 * KVB) & (SEQ - 1));
        __builtin_amdgcn_sched_barrier(0);
        compute(kfB, vfB);
    }

    // ---- write ctx (bf16, padded [s][448] layout) ----
#pragma unroll
    for (int r = 0; r < 4; ++r) {
        float inv = 1.0f / lrow[r];
        int q = q0 + lg * 4 + r;
        ushort* dst = ctx + ((size_t)(b << 10) + q) * KP + s0;
#pragma unroll
        for (int dt = 0; dt < NDT; ++dt) {
            int dv = lr + 16 * dt;
            if (dv < d) dst[dv] = f2bf(o[dt][r] * inv);
        }
    }
}

__global__ __launch_bounds__(128, 2)
void attn_mfma(const ushort* __restrict__ qp, const ushort* __restrict__ kp,
               const ushort* __restrict__ vp, ushort* __restrict__ ctx)
{
    __shared__ ushort Ps[2][16 * 64];        // 4 KB / 2-wave workgroup
    int wave = threadIdx.x >> 6;
    // XCD-group swizzle: all 32 WGs of one (b,h) land on one XCD.
    // 4608 WGs = 8 xcd x 576 slots; 144 groups = 8 x 18 — bijective.
    int i = blockIdx.x;
    int xcd = i & 7, slot = i >> 3;          // slot 0..575
    int group = xcd + 8 * (slot >> 5);       // 0..143
    int sub = slot & 31;                     // 32-row tile within group
    int b = group / NH, h = group % NH;
    int q0 = sub * 32 + wave * 16;
    if (h < 3)      attn_body<32, 64>(qp, kp, vp, ctx, Ps[wave], h, b, q0);
    else if (h < 7) attn_body<64, 64>(qp, kp, vp, ctx, Ps[wave], h, b, q0);
    else            attn_body<96, 32>(qp, kp, vp, ctx, Ps[wave], h, b, q0);
}

// ---------------------------------------------------------------------------
extern "C" void kernel_launch(void* const* d_in, const int* in_sizes, int n_in,
                              void* d_out, int out_size, void* d_ws, size_t ws_size,
                              hipStream_t stream)
{
    const float* hs = (const float*)d_in[0];
    const float* Wq = (const float*)d_in[1];
    const float* bq = (const float*)d_in[2];
    const float* Wk = (const float*)d_in[3];
    const float* bk = (const float*)d_in[4];
    const float* Wv = (const float*)d_in[5];
    const float* bv = (const float*)d_in[6];
    const float* Wo = (const float*)d_in[7];
    const float* bo = (const float*)d_in[8];

    size_t pelem = (size_t)BATCH * PBE;            // 8,912,896 per tensor
    ushort* qp  = (ushort*)d_ws;
    ushort* kp  = qp + pelem;
    ushort* vp  = kp + pelem;
    ushort* ctx = vp + pelem;                      // bf16 [16384][448]
    ushort* wt  = ctx + (size_t)BATCH * SEQ * KP;  // 4 x [448][448] bf16
    ushort* hsb = (ushort*)d_out;                  // bf16 hs, dead before final GEMM writes

    // zero q/k/v pads + ctx pad cols (contiguous region)
    hipMemsetAsync(d_ws, 0, (3 * pelem + (size_t)BATCH * SEQ * KP) * sizeof(ushort), stream);

    convert_hs<<<BATCH * SEQ * 56 / 256, 256, 0, stream>>>(hs, hsb);
    convert_w<<<dim3(KP * 56 / 256, 4), 256, 0, stream>>>(Wq, Wk, Wv, Wo, wt);

    dim3 gg(BATCH * SEQ / 128, KP / 64);           // 128 x 7
    gemm_mfma<0><<<gg, 256, 0, stream>>>(hsb, wt + 0 * (size_t)WTS, bq, qp);  // Q (pre-scaled)
    gemm_mfma<3><<<gg, 256, 0, stream>>>(hsb, wt + 1 * (size_t)WTS, bk, kp);  // K
    gemm_mfma<1><<<gg, 256, 0, stream>>>(hsb, wt + 2 * (size_t)WTS, bv, vp);  // V (transposed)

    attn_mfma<<<SEQ / 32 * NH * BATCH, 128, 0, stream>>>(qp, kp, vp, ctx);

    gemm_mfma<2><<<gg, 256, 0, stream>>>(ctx, wt + 3 * (size_t)WTS, bo, d_out);
}

// Round 11
// 242.747 us; speedup vs baseline: 1.4548x; 1.4548x over previous
//
#include <hip/hip_runtime.h>
#include <math.h>

#define BATCH 16
#define SEQ   1024
#define HID   441
#define NH    9
#define KP    448                 // padded hidden (K and N dim of GEMMs)
#define PB    544                 // sum of padded head dims
#define PBE   (SEQ * PB)          // padded elems per batch
#define WTS   (KP * KP)           // one transposed weight matrix

typedef __attribute__((ext_vector_type(8))) short bf16x8;
typedef __attribute__((ext_vector_type(4))) float f32x4;

__constant__ int c_bounds[NH + 1] = {0, 7, 21, 49, 105, 161, 217, 273, 357, 441};
__constant__ int c_dpad[NH] = {32, 32, 32, 64, 64, 64, 64, 96, 96};
__constant__ int c_cum[NH]  = {0, 32, 64, 96, 160, 224, 288, 352, 448};

__device__ __forceinline__ ushort f2bf(float x) {
    union { float f; unsigned u; } v; v.f = x;
    unsigned r = v.u + 0x7FFF + ((v.u >> 16) & 1);   // RNE
    return (ushort)(r >> 16);
}

__device__ __forceinline__ void gld_lds16(const ushort* g, ushort* l) {
    __builtin_amdgcn_global_load_lds(
        (const __attribute__((address_space(1))) unsigned int*)g,
        (__attribute__((address_space(3))) unsigned int*)l, 16, 0, 0);
}

// ---------------------------------------------------------------------------
// hs fp32 [16384][441] -> bf16 [16384][448] (pad cols zeroed)
// ---------------------------------------------------------------------------
__global__ __launch_bounds__(256)
void convert_hs(const float* __restrict__ hs, ushort* __restrict__ out)
{
    int t = blockIdx.x * 256 + threadIdx.x;   // 16384*56 threads
    int r = t / 56, cc = t % 56;
    const float* src = hs + (size_t)r * HID + cc * 8;
    union { ushort u[8]; bf16x8 v; } pk;
#pragma unroll
    for (int j = 0; j < 8; ++j) {
        int c = cc * 8 + j;
        pk.u[j] = (c < HID) ? f2bf(src[j]) : (ushort)0;
    }
    *(bf16x8*)(out + (size_t)r * KP + cc * 8) = pk.v;
}

// ---------------------------------------------------------------------------
// W fp32 [441][441] -> W^T bf16 [448][448] (pads zero). blockIdx.y = matrix.
// ---------------------------------------------------------------------------
__global__ __launch_bounds__(256)
void convert_w(const float* __restrict__ W0, const float* __restrict__ W1,
               const float* __restrict__ W2, const float* __restrict__ W3,
               ushort* __restrict__ wt)
{
    const float* W = (blockIdx.y == 0) ? W0 : (blockIdx.y == 1) ? W1
                   : (blockIdx.y == 2) ? W2 : W3;
    ushort* out = wt + (size_t)blockIdx.y * WTS;
    int t = blockIdx.x * 256 + threadIdx.x;   // 448*56 threads
    int n = t / 56, kc = t % 56;
    union { ushort u[8]; bf16x8 v; } pk;
#pragma unroll
    for (int j = 0; j < 8; ++j) {
        int k = kc * 8 + j;
        pk.u[j] = (k < HID && n < HID) ? f2bf(W[(size_t)k * HID + n]) : (ushort)0;
    }
    *(bf16x8*)(out + (size_t)n * KP + kc * 8) = pk.v;
}

// ---------------------------------------------------------------------------
// bf16 MFMA GEMM: C[16384, 448] = A[16384, 448] @ Bt[448, 448]^T + bias
// Tile 128x64, BK=32, 4 waves (2x2), global_load_lds staging, 1 barrier/step.
// MODE 0: Q — bf16 scatter -> padded [b][h][s][dp], PRE-SCALED by log2e/sqrt(d)
// MODE 3: K — bf16 scatter -> padded [b][h][s][dp], unscaled
// MODE 1: V — bf16 scatter -> transposed [b][h][dv][s]
// MODE 2: O — fp32 row-major [16384][441] + bias
// ---------------------------------------------------------------------------
template<int MODE>
__global__ __launch_bounds__(256)
void gemm_mfma(const ushort* __restrict__ A, const ushort* __restrict__ Bt,
               const float* __restrict__ bias, void* __restrict__ Cout)
{
    __shared__ ushort As[2][128 * 32];   // per buffer: 128 rows x 32 K = 4096 ushorts
    __shared__ ushort Bs[2][64 * 32];

    int tid = threadIdx.x;
    int wid = tid >> 6, lane = tid & 63;
    int wm = wid >> 1, wn = wid & 1;
    int lr = lane & 15, lg = lane >> 4;
    int m0 = blockIdx.x * 128, n0 = blockIdx.y * 64;

    const ushort* a_src = A + (size_t)(m0 + (tid >> 2)) * KP + (tid & 3) * 8;
    const ushort* b_src = Bt + (size_t)(n0 + (tid >> 2)) * KP + (tid & 3) * 8;

    f32x4 acc[4][2];
#pragma unroll
    for (int i = 0; i < 4; ++i)
#pragma unroll
        for (int j = 0; j < 2; ++j) acc[i][j] = (f32x4){0.f, 0.f, 0.f, 0.f};

    auto stage = [&](int buf, int k0) {
        gld_lds16(a_src + k0,            &As[buf][tid * 8]);
        gld_lds16(a_src + 64 * KP + k0,  &As[buf][2048 + tid * 8]);
        gld_lds16(b_src + k0,            &Bs[buf][tid * 8]);
    };

    stage(0, 0);
#pragma unroll 2
    for (int t = 0; t < 14; ++t) {
        int buf = t & 1;
        __syncthreads();                       // drains vmcnt+lgkm: buf staged, prev reads done
        if (t < 13) stage(buf ^ 1, (t + 1) * 32);

        bf16x8 af[4], bf[2];
#pragma unroll
        for (int mr = 0; mr < 4; ++mr)
            af[mr] = *(const bf16x8*)&As[buf][(wm * 64 + mr * 16 + lr) * 32 + lg * 8];
#pragma unroll
        for (int nt = 0; nt < 2; ++nt)
            bf[nt] = *(const bf16x8*)&Bs[buf][(wn * 32 + nt * 16 + lr) * 32 + lg * 8];
#pragma unroll
        for (int mr = 0; mr < 4; ++mr)
#pragma unroll
            for (int nt = 0; nt < 2; ++nt)
                acc[mr][nt] = __builtin_amdgcn_mfma_f32_16x16x32_bf16(af[mr], bf[nt], acc[mr][nt], 0, 0, 0);
    }

    // ---- epilogue ----
    int bb = m0 >> 10;
    int srow = (m0 & 1023) + wm * 64;

#pragma unroll
    for (int nt = 0; nt < 2; ++nt) {
        int gn = n0 + wn * 32 + nt * 16 + lr;
        bool ok = gn < HID;
        int gcl = ok ? gn : 0;
        float bval = ok ? bias[gcl] : 0.f;
        int hh = 0;
        while (gcl >= c_bounds[hh + 1]) ++hh;
        int off = gcl - c_bounds[hh];
        int dph = c_dpad[hh];
        size_t hbase = (size_t)bb * PBE + ((size_t)c_cum[hh] << 10);
        // Q pre-scale: fold log2e / sqrt(d) into Q so attention needs no score mul
        float cs = (MODE == 0)
                 ? rsqrtf((float)(c_bounds[hh + 1] - c_bounds[hh])) * 1.44269504f
                 : 1.0f;

#pragma unroll
        for (int mr = 0; mr < 4; ++mr)
#pragma unroll
            for (int r = 0; r < 4; ++r) {
                if (!ok) continue;
                int s = srow + mr * 16 + lg * 4 + r;
                float val = (acc[mr][nt][r] + bval) * cs;
                if (MODE == 0 || MODE == 3) {
                    ((ushort*)Cout)[hbase + (size_t)s * dph + off] = f2bf(val);
                } else if (MODE == 1) {
                    ((ushort*)Cout)[hbase + ((size_t)off << 10) + s] = f2bf(val);
                } else {
                    ((float*)Cout)[(size_t)(m0 + wm * 64 + mr * 16 + lg * 4 + r) * HID + gn] = val;
                }
            }
    }
}

// ---------------------------------------------------------------------------
// LDS chunk swizzle (16B units). Stage side uses the same involution on the
// GLOBAL source chunk (global_load_lds writes linearly — rule #21), read side
// applies it to the logical chunk index.
// ---------------------------------------------------------------------------
template<int DP>
__device__ __forceinline__ int kswz(int j, int rho) {
    if constexpr (DP == 32)      return j ^ (rho & 3);            // 4 chunks/row
    else if constexpr (DP == 64) return j ^ (rho & 7);            // 8 chunks/row
    else                         return (j & ~3) | ((j & 3) ^ (rho & 3)); // 12 chunks/row, XOR within 4-groups
}

// Stage one K tile (64 keys x DP) and one V^T tile (DP rows x 64 keys) into LDS.
// 512 threads. LDS dest linear (lane x 16B); global src chunk pre-swizzled.
template<int DP>
__device__ __forceinline__
void stage_tiles(const ushort* __restrict__ Kb, const ushort* __restrict__ Vtb,
                 ushort* __restrict__ lds, int buf, int kt, int tid)
{
    constexpr int TILE = 64 * DP;
    ushort* kdst = lds + buf * TILE;
    ushort* vdst = lds + (2 + buf) * TILE;

    // ---- K tile: 64 rows x DP elems ----
    if constexpr (DP == 32) {
        if (tid < 256) {                       // waves 0-3
            int r = tid >> 2, c = tid & 3;
            gld_lds16(Kb + (size_t)(kt + r) * DP + ((c ^ (r & 3)) * 8), kdst + tid * 8);
        }
    } else if constexpr (DP == 64) {
        int r = tid >> 3, c = tid & 7;
        gld_lds16(Kb + (size_t)(kt + r) * DP + ((c ^ (r & 7)) * 8), kdst + tid * 8);
    } else {                                   // DP == 96: 768 chunks in 2 passes
        {
            int r = tid / 12, c = tid - r * 12;
            int cs = (c & ~3) | ((c & 3) ^ (r & 3));
            gld_lds16(Kb + (size_t)(kt + r) * DP + cs * 8, kdst + tid * 8);
        }
        if (tid < 256) {
            int L = 512 + tid;
            int r = L / 12, c = L - r * 12;
            int cs = (c & ~3) | ((c & 3) ^ (r & 3));
            gld_lds16(Kb + (size_t)(kt + r) * DP + cs * 8, kdst + L * 8);
        }
    }

    // ---- V^T tile: DP rows x 64 keys (8 chunks/row for all DP) ----
    if constexpr (DP == 32) {
        if (tid >= 256) {                      // waves 4-7
            int t = tid - 256;
            int r = t >> 3, c = t & 7;
            gld_lds16(Vtb + ((size_t)r << 10) + kt + ((c ^ (r & 7)) * 8), vdst + t * 8);
        }
    } else if constexpr (DP == 64) {
        int r = tid >> 3, c = tid & 7;
        gld_lds16(Vtb + ((size_t)r << 10) + kt + ((c ^ (r & 7)) * 8), vdst + tid * 8);
    } else {
        {
            int r = tid >> 3, c = tid & 7;
            gld_lds16(Vtb + ((size_t)r << 10) + kt + ((c ^ (r & 7)) * 8), vdst + tid * 8);
        }
        if (tid < 256) {
            int L = 512 + tid;
            int r = L >> 3, c = L & 7;
            gld_lds16(Vtb + ((size_t)r << 10) + kt + ((c ^ (r & 7)) * 8), vdst + L * 8);
        }
    }
}

// ---------------------------------------------------------------------------
// MFMA flash attention, cooperative: block = (b, h, 128 q-rows), 8 waves x 16q.
// K + V^T tiles (64 keys) double-buffered in LDS via global_load_lds; stage of
// tile t+1 issued right after the barrier, flies under compute of tile t
// (gemm_mfma's proven 1-barrier-per-step pipeline). K/V L2 traffic / 8.
// Q pre-scaled (exp2 domain); per-wave softmax + swizzled Ps bounce unchanged.
// ---------------------------------------------------------------------------
template<int DP>
__device__ __forceinline__
void attn_body(const ushort* __restrict__ qp, const ushort* __restrict__ kp,
               const ushort* __restrict__ vp, ushort* __restrict__ ctx,
               ushort* __restrict__ lds, int h, int b, int q0blk, int tid)
{
    constexpr int NDT  = DP / 16;        // output col tiles (2/4/6)
    constexpr int NXC  = DP / 32;        // K-dim chunks for QK (1/2/3)
    constexpr int TILE = 64 * DP;

    int wave = tid >> 6, lane = tid & 63;
    int lr = lane & 15, lg = lane >> 4;
    int q0 = q0blk + wave * 16;

    int s0 = c_bounds[h];
    int d  = c_bounds[h + 1] - s0;

    size_t base = (size_t)b * PBE + ((size_t)c_cum[h] << 10);
    const ushort* Qb  = qp + base;
    const ushort* Kb  = kp + base;
    const ushort* Vtb = vp + base;

    ushort* Ps = lds + 4 * TILE + wave * 1024;   // per-wave 16x64 P tile
    int swz = (lr & 7) << 3;

    bf16x8 aq[NXC];
    {
        int qrow = q0 + lr;
        const ushort* qr = Qb + (size_t)qrow * DP + lg * 8;
#pragma unroll
        for (int xc = 0; xc < NXC; ++xc)
            aq[xc] = *(const bf16x8*)(qr + xc * 32);
    }

    f32x4 o[NDT];
#pragma unroll
    for (int i = 0; i < NDT; ++i) o[i] = (f32x4){0.f, 0.f, 0.f, 0.f};
    float mrow[4] = {-1e30f, -1e30f, -1e30f, -1e30f};
    float lrow[4] = {0.f, 0.f, 0.f, 0.f};

    stage_tiles<DP>(Kb, Vtb, lds, 0, 0, tid);
    int buf = 0;
    for (int t = 0; t < SEQ / 64; ++t) {
        __syncthreads();                 // buf staged (vmcnt drained) & prev reads done
        if (t < SEQ / 64 - 1)
            stage_tiles<DP>(Kb, Vtb, lds, buf ^ 1, (t + 1) * 64, tid);

        const ushort* kb = lds + buf * TILE;
        const ushort* vb = lds + (2 + buf) * TILE;

        // ---- S = Q K^T : 16 q x 64 keys (exp2-scaled via Q) ----
        f32x4 sc[4];
        __builtin_amdgcn_s_setprio(1);
#pragma unroll
        for (int ct = 0; ct < 4; ++ct) {
            f32x4 s = {0.f, 0.f, 0.f, 0.f};
            int rho = ct * 16 + lr;
#pragma unroll
            for (int xc = 0; xc < NXC; ++xc) {
                int jj = lg + 4 * xc;
                bf16x8 bk = *(const bf16x8*)&kb[rho * DP + kswz<DP>(jj, rho) * 8];
                s = __builtin_amdgcn_mfma_f32_16x16x32_bf16(aq[xc], bk, s, 0, 0, 0);
            }
            sc[ct] = s;
        }
        __builtin_amdgcn_s_setprio(0);

        // ---- online softmax ----
        float mnew[4], fr[4];
#pragma unroll
        for (int r = 0; r < 4; ++r) {
            float mx = fmaxf(fmaxf(sc[0][r], sc[1][r]), fmaxf(sc[2][r], sc[3][r]));
#pragma unroll
            for (int off = 1; off < 16; off <<= 1)
                mx = fmaxf(mx, __shfl_xor(mx, off));
            mnew[r] = fmaxf(mrow[r], mx);
            fr[r] = exp2f(mrow[r] - mnew[r]);
            mrow[r] = mnew[r];
        }
#pragma unroll
        for (int r = 0; r < 4; ++r) {
            int row = lg * 4 + r;
            int wsz = (row & 7) << 3;
            float sum = 0.f;
#pragma unroll
            for (int ct = 0; ct < 4; ++ct) {
                float p = exp2f(sc[ct][r] - mnew[r]);
                sum += p;
                Ps[row * 64 + ((lr + ct * 16) ^ wsz)] =
                    (ushort)((__builtin_bit_cast(unsigned, p) + 0x8000u) >> 16);
            }
#pragma unroll
            for (int off = 1; off < 16; off <<= 1)
                sum += __shfl_xor(sum, off);
            lrow[r] = lrow[r] * fr[r] + sum;
        }

        // ---- O = fr*O + P V ----
        bf16x8 ap[2];
#pragma unroll
        for (int ks = 0; ks < 2; ++ks)
            ap[ks] = *(const bf16x8*)&Ps[lr * 64 + ((ks * 32 + lg * 8) ^ swz)];

        __builtin_amdgcn_s_setprio(1);
#pragma unroll
        for (int dt = 0; dt < NDT; ++dt) {
            int rv = dt * 16 + lr;
#pragma unroll
            for (int r = 0; r < 4; ++r) o[dt][r] *= fr[r];
#pragma unroll
            for (int ks = 0; ks < 2; ++ks) {
                int jj = lg + 4 * ks;
                bf16x8 bv = *(const bf16x8*)&vb[rv * 64 + ((jj ^ (rv & 7)) * 8)];
                o[dt] = __builtin_amdgcn_mfma_f32_16x16x32_bf16(ap[ks], bv, o[dt], 0, 0, 0);
            }
        }
        __builtin_amdgcn_s_setprio(0);
        buf ^= 1;
    }

    // ---- write ctx (bf16, padded [s][448] layout) ----
#pragma unroll
    for (int r = 0; r < 4; ++r) {
        float inv = 1.0f / lrow[r];
        int q = q0 + lg * 4 + r;
        ushort* dst = ctx + ((size_t)(b << 10) + q) * KP + s0;
#pragma unroll
        for (int dt = 0; dt < NDT; ++dt) {
            int dv = lr + 16 * dt;
            if (dv < d) dst[dv] = f2bf(o[dt][r] * inv);
        }
    }
}

__global__ __launch_bounds__(512, 4)
void attn_mfma(const ushort* __restrict__ qp, const ushort* __restrict__ kp,
               const ushort* __restrict__ vp, ushort* __restrict__ ctx)
{
    __shared__ ushort lds[32768];            // 64 KB: K dbuf | V dbuf | 8x Ps
    int tid = threadIdx.x;
    // XCD-group swizzle: all 8 q-blocks of one (b,h) on one XCD.
    // 1152 blocks = 8 xcd x 144; 144 groups = 8 x 18 — bijective.
    int i = blockIdx.x;
    int xcd = i & 7, j = i >> 3;             // j 0..143
    int g = xcd + 8 * (j % 18);              // 0..143
    int qblk = j / 18;                       // 0..7
    int b = g / NH, h = g % NH;
    int q0 = qblk * 128;
    if (h < 3)      attn_body<32>(qp, kp, vp, ctx, lds, h, b, q0, tid);
    else if (h < 7) attn_body<64>(qp, kp, vp, ctx, lds, h, b, q0, tid);
    else            attn_body<96>(qp, kp, vp, ctx, lds, h, b, q0, tid);
}

// ---------------------------------------------------------------------------
extern "C" void kernel_launch(void* const* d_in, const int* in_sizes, int n_in,
                              void* d_out, int out_size, void* d_ws, size_t ws_size,
                              hipStream_t stream)
{
    const float* hs = (const float*)d_in[0];
    const float* Wq = (const float*)d_in[1];
    const float* bq = (const float*)d_in[2];
    const float* Wk = (const float*)d_in[3];
    const float* bk = (const float*)d_in[4];
    const float* Wv = (const float*)d_in[5];
    const float* bv = (const float*)d_in[6];
    const float* Wo = (const float*)d_in[7];
    const float* bo = (const float*)d_in[8];

    size_t pelem = (size_t)BATCH * PBE;            // 8,912,896 per tensor
    ushort* qp  = (ushort*)d_ws;
    ushort* kp  = qp + pelem;
    ushort* vp  = kp + pelem;
    ushort* ctx = vp + pelem;                      // bf16 [16384][448]
    ushort* wt  = ctx + (size_t)BATCH * SEQ * KP;  // 4 x [448][448] bf16
    ushort* hsb = (ushort*)d_out;                  // bf16 hs, dead before final GEMM writes

    // zero q/k/v pads + ctx pad cols (contiguous region)
    hipMemsetAsync(d_ws, 0, (3 * pelem + (size_t)BATCH * SEQ * KP) * sizeof(ushort), stream);

    convert_hs<<<BATCH * SEQ * 56 / 256, 256, 0, stream>>>(hs, hsb);
    convert_w<<<dim3(KP * 56 / 256, 4), 256, 0, stream>>>(Wq, Wk, Wv, Wo, wt);

    dim3 gg(BATCH * SEQ / 128, KP / 64);           // 128 x 7
    gemm_mfma<0><<<gg, 256, 0, stream>>>(hsb, wt + 0 * (size_t)WTS, bq, qp);  // Q (pre-scaled)
    gemm_mfma<3><<<gg, 256, 0, stream>>>(hsb, wt + 1 * (size_t)WTS, bk, kp);  // K
    gemm_mfma<1><<<gg, 256, 0, stream>>>(hsb, wt + 2 * (size_t)WTS, bv, vp);  // V (transposed)

    attn_mfma<<<8 * 144, 512, 0, stream>>>(qp, kp, vp, ctx);

    gemm_mfma<2><<<gg, 256, 0, stream>>>(ctx, wt + 3 * (size_t)WTS, bo, d_out);
}